// Round 7
// baseline (413.932 us; speedup 1.0000x reference)
//
#include <hip/hip_runtime.h>

// Circular conv1d: x (B=64, C_in=8, L=65536) fp32, W (8,8,4), b (8,).
// Memory-bound, ~200MB mandatory HBM traffic -> ~32-35us floor at copy
// ceiling. R2/R4 plateau at 50us = unhidden load latency (no loads in
// flight during FMA phases). R5/R6 tried to pipeline but arrays/macro
// loops got demoted to scratch (FETCH/WRITE blew up 4-5x, VALUBusy ~5%).
// This version: NAMED REGISTERS ONLY - no arrays, no ref-param helpers,
// no loops inside macros. 8 loads in flight at peak, 4 sustained under
// every 512-cycle FMA block. launch_bounds(256,5) caps VGPR at 102,
// forcing the interleave to survive scheduling.
#define BATCH 64
#define CIN 8
#define COUT 8
#define LEN 65536
#define FS 4
#define NBLOCKS 4096
#define NTHREADS 256

typedef float floatx4 __attribute__((ext_vector_type(4)));

// one output channel, 4 positions, 4 taps from x0..x6
#define COMP1(ACC, WV)                                              \
    ACC.x += (WV).x * x0 + (WV).y * x1 + (WV).z * x2 + (WV).w * x3; \
    ACC.y += (WV).x * x1 + (WV).y * x2 + (WV).z * x3 + (WV).w * x4; \
    ACC.z += (WV).x * x2 + (WV).y * x3 + (WV).z * x4 + (WV).w * x5; \
    ACC.w += (WV).x * x3 + (WV).y * x4 + (WV).z * x5 + (WV).w * x6;

// one input channel CI (data in LO/HI), all 8 output channels
#define COMP(LO, HI, CI)                                            \
    do {                                                            \
        const float x0 = (LO).x, x1 = (LO).y, x2 = (LO).z,          \
                    x3 = (LO).w, x4 = (HI).x, x5 = (HI).y,          \
                    x6 = (HI).z;                                    \
        const floatx4 w0 = sWv[0 * CIN + (CI)];                     \
        const floatx4 w1 = sWv[1 * CIN + (CI)];                     \
        const floatx4 w2 = sWv[2 * CIN + (CI)];                     \
        const floatx4 w3 = sWv[3 * CIN + (CI)];                     \
        const floatx4 w4 = sWv[4 * CIN + (CI)];                     \
        const floatx4 w5 = sWv[5 * CIN + (CI)];                     \
        const floatx4 w6 = sWv[6 * CIN + (CI)];                     \
        const floatx4 w7 = sWv[7 * CIN + (CI)];                     \
        COMP1(acc0, w0) COMP1(acc1, w1) COMP1(acc2, w2)             \
        COMP1(acc3, w3) COMP1(acc4, w4) COMP1(acc5, w5)             \
        COMP1(acc6, w6) COMP1(acc7, w7)                             \
    } while (0)

// load one channel CI into two named float4 regs (offsets o0 / o1)
#define LD(R0, R1, CI)                                                        \
    R0 = *reinterpret_cast<const floatx4*>(xb + ((size_t)(CI) << 16) + l0);   \
    R1 = *reinterpret_cast<const floatx4*>(xb + ((size_t)(CI) << 16) + o1);

__global__ __launch_bounds__(256, 5) void conv_pbc_kernel(
    const float* __restrict__ x,
    const float* __restrict__ W,
    const float* __restrict__ bias,
    float* __restrict__ out)
{
    __shared__ floatx4 sWv[COUT * CIN];   // (co,ci) -> 4 taps
    __shared__ float sB[COUT];

    const int tid = threadIdx.x;
    if (tid < COUT * CIN) sWv[tid] = *reinterpret_cast<const floatx4*>(W + tid * FS);
    if (tid < COUT)       sB[tid] = bias[tid];
    __syncthreads();

    const int g  = blockIdx.x * NTHREADS + tid;     // 1M threads, 1 tile each
    const int b  = g >> 14;                         // batch
    const int l0 = (g & 16383) << 2;                // first of 4 positions
    const int o1 = (l0 + 4) & (LEN - 1);            // branch-free circular wrap
    const float* xb = x + ((size_t)b << 19);        // b * CIN*LEN

    floatx4 a0, a1, a2, a3, b0, b1, b2, b3;

    // prologue: channels 0-3 in flight (8 loads)
    LD(a0, a1, 0) LD(a2, a3, 1)
    LD(b0, b1, 2) LD(b2, b3, 3)

    floatx4 acc0 = {sB[0], sB[0], sB[0], sB[0]};
    floatx4 acc1 = {sB[1], sB[1], sB[1], sB[1]};
    floatx4 acc2 = {sB[2], sB[2], sB[2], sB[2]};
    floatx4 acc3 = {sB[3], sB[3], sB[3], sB[3]};
    floatx4 acc4 = {sB[4], sB[4], sB[4], sB[4]};
    floatx4 acc5 = {sB[5], sB[5], sB[5], sB[5]};
    floatx4 acc6 = {sB[6], sB[6], sB[6], sB[6]};
    floatx4 acc7 = {sB[7], sB[7], sB[7], sB[7]};

    COMP(a0, a1, 0);                 // waits ch0 only; ch1-3 still in flight
    COMP(a2, a3, 1);
    LD(a0, a1, 4) LD(a2, a3, 5)      // ch4,5 in flight under ch2,3 compute
    COMP(b0, b1, 2);
    COMP(b2, b3, 3);
    LD(b0, b1, 6) LD(b2, b3, 7)      // ch6,7 in flight under ch4,5 compute
    COMP(a0, a1, 4);
    COMP(a2, a3, 5);
    COMP(b0, b1, 6);
    COMP(b2, b3, 7);

    // nontemporal stores: out is never re-read; keep L3 for x
    float* ob = out + ((size_t)b << 19) + l0;
    __builtin_nontemporal_store(acc0, reinterpret_cast<floatx4*>(ob + (0 << 16)));
    __builtin_nontemporal_store(acc1, reinterpret_cast<floatx4*>(ob + (1 << 16)));
    __builtin_nontemporal_store(acc2, reinterpret_cast<floatx4*>(ob + (2 << 16)));
    __builtin_nontemporal_store(acc3, reinterpret_cast<floatx4*>(ob + (3 << 16)));
    __builtin_nontemporal_store(acc4, reinterpret_cast<floatx4*>(ob + (4 << 16)));
    __builtin_nontemporal_store(acc5, reinterpret_cast<floatx4*>(ob + (5 << 16)));
    __builtin_nontemporal_store(acc6, reinterpret_cast<floatx4*>(ob + (6 << 16)));
    __builtin_nontemporal_store(acc7, reinterpret_cast<floatx4*>(ob + (7 << 16)));
}

extern "C" void kernel_launch(void* const* d_in, const int* in_sizes, int n_in,
                              void* d_out, int out_size, void* d_ws, size_t ws_size,
                              hipStream_t stream) {
    const float* x    = (const float*)d_in[0];
    const float* W    = (const float*)d_in[1];
    const float* bias = (const float*)d_in[2];
    float* out = (float*)d_out;

    conv_pbc_kernel<<<dim3(NBLOCKS), dim3(NTHREADS), 0, stream>>>(x, W, bias, out);
}

// Round 8
// 234.783 us; speedup vs baseline: 1.7630x; 1.7630x over previous
//
#include <hip/hip_runtime.h>

// Circular conv1d: x (B=64, C_in=8, L=65536) fp32, W (8,8,4), b (8,).
// Memory-bound; ~200MB mandatory HBM traffic -> ~32us floor.
// History: R2 (unroll 2, clean codegen) = 50us @ 4 TB/s. R5/R6/R7 hand
// pipelines all died the same way: scheduler hoists independent loads
// into one clause -> pressure > waves_per_eu budget -> loaded values
// spilled to scratch (GB-scale FETCH/WRITE, VALUBusy ~5%). Lesson: do
// NOT hand-interleave; let natural unroll clause the loads.
// This round: R2 body, two minimal changes:
//   1) unroll 4 (8 float4 loads per clause, ~2x in-flight bytes/wave)
//   2) 2048 persistent-ish blocks x 2 grid-strided tiles (halve dispatch
//      churn; blocks live 2x longer)
#define BATCH 64
#define CIN 8
#define COUT 8
#define LEN 65536
#define FS 4
#define TILE 1024                  // positions per block-iteration (256 x 4)
#define TILES_PER_B (LEN / TILE)   // 64
#define NTILES (BATCH * TILES_PER_B)  // 4096 block-tiles
#define NBLOCKS 2048
#define ITERS (NTILES / NBLOCKS)   // 2

typedef float floatx4 __attribute__((ext_vector_type(4)));

__global__ __launch_bounds__(256, 4) void conv_pbc_kernel(
    const float* __restrict__ x,
    const float* __restrict__ W,
    const float* __restrict__ bias,
    float* __restrict__ out)
{
    __shared__ float sW[COUT * CIN * FS];   // 256 floats
    __shared__ float sB[COUT];

    const int tid = threadIdx.x;
    if (tid < COUT * CIN * FS) sW[tid] = W[tid];
    if (tid < COUT)            sB[tid] = bias[tid];
    __syncthreads();

#pragma unroll
    for (int t = 0; t < ITERS; ++t) {
        const int G    = blockIdx.x + t * NBLOCKS;    // global tile index
        const int b    = G >> 6;                      // / TILES_PER_B
        const int tile = G & (TILES_PER_B - 1);
        const int l0   = tile * TILE + tid * 4;

        const float* xb = x + ((size_t)b << 19);      // b * CIN*LEN

        float acc[COUT][4];
#pragma unroll
        for (int co = 0; co < COUT; ++co) {
            const float bb = sB[co];
            acc[co][0] = bb; acc[co][1] = bb; acc[co][2] = bb; acc[co][3] = bb;
        }

        const bool fast = (l0 + 8 <= LEN);

#pragma unroll 4
        for (int ci = 0; ci < CIN; ++ci) {
            const float* xc = xb + ((size_t)ci << 16);
            float xv[8];
            if (fast) {
                const floatx4 v0 = *reinterpret_cast<const floatx4*>(xc + l0);
                const floatx4 v1 = *reinterpret_cast<const floatx4*>(xc + l0 + 4);
                xv[0] = v0.x; xv[1] = v0.y; xv[2] = v0.z; xv[3] = v0.w;
                xv[4] = v1.x; xv[5] = v1.y; xv[6] = v1.z; xv[7] = v1.w;
            } else {
                // circular wrap (only the last thread-tile of each batch row)
#pragma unroll
                for (int j = 0; j < 8; ++j)
                    xv[j] = xc[(l0 + j) & (LEN - 1)];
            }

#pragma unroll
            for (int co = 0; co < COUT; ++co) {
#pragma unroll
                for (int k = 0; k < FS; ++k) {
                    const float w = sW[(co * CIN + ci) * FS + k];  // uniform
#pragma unroll
                    for (int p = 0; p < 4; ++p)
                        acc[co][p] += w * xv[p + k];
                }
            }
        }

        // nontemporal: out is never re-read; keep L3 for x
        float* ob = out + ((size_t)b << 19) + l0;
#pragma unroll
        for (int co = 0; co < COUT; ++co) {
            const floatx4 v = {acc[co][0], acc[co][1], acc[co][2], acc[co][3]};
            __builtin_nontemporal_store(v, reinterpret_cast<floatx4*>(ob + ((size_t)co << 16)));
        }
    }
}

extern "C" void kernel_launch(void* const* d_in, const int* in_sizes, int n_in,
                              void* d_out, int out_size, void* d_ws, size_t ws_size,
                              hipStream_t stream) {
    const float* x    = (const float*)d_in[0];
    const float* W    = (const float*)d_in[1];
    const float* bias = (const float*)d_in[2];
    float* out = (float*)d_out;

    conv_pbc_kernel<<<dim3(NBLOCKS), dim3(256), 0, stream>>>(x, W, bias, out);
}

// Round 9
// 58.285 us; speedup vs baseline: 7.1019x; 4.0282x over previous
//
#include <hip/hip_runtime.h>
#include <stdint.h>

// Circular conv1d: x (B=64, C_in=8, L=65536) fp32, W (8,8,4), b (8,).
// Memory-bound, ~200MB HBM traffic -> ~32us floor. R2/R4 = 50us: loads
// never in flight during compute (compiler drains vmcnt(0) at barriers /
// doesn't pipeline across iterations). R6-R8 spilled because
// __launch_bounds__(256,N) only sets MIN waves/EU -> allocator targeted a
// HIGHER occupancy step and spilled to reach it (R7: 48 VGPR, R8: 64 VGPR,
// both with GB-scale scratch). Fixes here:
//   1) amdgpu_waves_per_eu(4,4) pins the allocator target (128 VGPR cap).
//   2) Staging via __builtin_amdgcn_global_load_lds (width 16): loads go
//      straight to LDS, zero VGPR pressure, stay in flight across raw
//      s_barrier with counted s_waitcnt vmcnt(6)  (T3/T4 2-phase pattern).
//   3) Double-buffered LDS: tile t+1's 6 loads fly during tile t's compute.
// LDS layout per buffer: [ci][516]: 512 tile floats + 4 halo floats staged
// at [512..515] -> compute reads x[pp..pp+4] branch-free for all threads.
#define CIN 8
#define COUT 8
#define LEN 65536
#define FS 4
#define TILE 512
#define CSTRIDE 516                       // 512 + 4 halo floats
#define NBLOCKS 1024
#define NTILES 8192                       // 64 batches * 128 tiles
#define ITERS (NTILES / NBLOCKS)          // 8

typedef float floatx4 __attribute__((ext_vector_type(4)));
typedef float floatx2 __attribute__((ext_vector_type(2)));

#define GLOAD16(g, l)                                                        \
    __builtin_amdgcn_global_load_lds(                                        \
        (const __attribute__((address_space(1))) void*)(g),                  \
        (__attribute__((address_space(3))) void*)(l), 16, 0, 0)

__global__ __launch_bounds__(256)
__attribute__((amdgpu_waves_per_eu(4, 4)))
void conv_pbc_kernel(const float* __restrict__ x,
                     const float* __restrict__ W,
                     const float* __restrict__ bias,
                     float* __restrict__ out)
{
    __shared__ __align__(16) float sX[2][CIN * CSTRIDE];  // 2 x 16.1 KB
    __shared__ floatx4 sWv[COUT * CIN];                   // (co,ci) -> 4 taps
    __shared__ float   sB[COUT];

    const int tid  = threadIdx.x;
    const int wave = tid >> 6;
    const int lane = tid & 63;

    if (tid < COUT * CIN) sWv[tid] = *reinterpret_cast<const floatx4*>(W + tid * FS);
    if (tid < COUT)       sB[tid]  = bias[tid];
    __syncthreads();

    // Stage tile T into buffer P. Per wave: 4 main GLOAD16 (wave-uniform LDS
    // base + lane*16B, per-lane global addr) + 2 single-lane halo GLOAD16.
    // = 6 vmcnt entries per wave per stage, uniform across waves.
    auto stage = [&](int P, int T) {
        const int b  = T >> 7;                 // 128 tiles per batch row
        const int p0 = (T & 127) << 9;         // tile base position
        const float* xb = x + ((size_t)b << 19);
        const int c0 = wave * 2;               // this wave stages ch c0, c0+1
        const float* g0 = xb + ((size_t)c0 << 16) + p0;
        const float* g1 = xb + ((size_t)(c0 + 1) << 16) + p0;
        float* d0 = &sX[P][c0 * CSTRIDE];
        float* d1 = &sX[P][(c0 + 1) * CSTRIDE];
        GLOAD16(g0 + lane * 4,       d0);
        GLOAD16(g0 + 256 + lane * 4, d0 + 256);
        GLOAD16(g1 + lane * 4,       d1);
        GLOAD16(g1 + 256 + lane * 4, d1 + 256);
        const int hoff = (p0 + TILE) & (LEN - 1);   // circular halo source
        if (lane == 0) {
            GLOAD16(xb + ((size_t)c0 << 16) + hoff,       d0 + TILE);
            GLOAD16(xb + ((size_t)(c0 + 1) << 16) + hoff, d1 + TILE);
        }
    };

    int T = blockIdx.x;
    stage(0, T);                               // prologue

#pragma unroll 2
    for (int i = 0; i < ITERS; ++i) {
        const int P  = i & 1;
        const int Tn = T + NBLOCKS;
        if (i + 1 < ITERS) stage(P ^ 1, Tn);   // next tile's loads in flight

        // Wait ONLY for buffer P's 6 loads (the newest 6 may stay in
        // flight), then sync. Raw barrier: no vmcnt(0) drain.
        asm volatile("s_waitcnt vmcnt(6)\n\ts_barrier" ::: "memory");

        const int b  = T >> 7;
        const int p0 = (T & 127) << 9;
        const int pp = tid * 2;                // 2 output positions/thread

        float acc[COUT][2];
#pragma unroll
        for (int co = 0; co < COUT; ++co) { acc[co][0] = sB[co]; acc[co][1] = sB[co]; }

#pragma unroll
        for (int ci = 0; ci < CIN; ++ci) {
            const float* xc = &sX[P][ci * CSTRIDE + pp];
            const float x0 = xc[0], x1 = xc[1], x2 = xc[2], x3 = xc[3], x4 = xc[4];
#pragma unroll
            for (int co = 0; co < COUT; ++co) {
                const floatx4 w = sWv[co * CIN + ci];   // uniform broadcast
                acc[co][0] += w.x * x0 + w.y * x1 + w.z * x2 + w.w * x3;
                acc[co][1] += w.x * x1 + w.y * x2 + w.z * x3 + w.w * x4;
            }
        }

        float* ob = out + ((size_t)b << 19) + p0 + pp;
#pragma unroll
        for (int co = 0; co < COUT; ++co) {
            const floatx2 v = {acc[co][0], acc[co][1]};
            __builtin_nontemporal_store(v, reinterpret_cast<floatx2*>(ob + ((size_t)co << 16)));
        }

        // All waves done reading buffer P before next iter overwrites it.
        asm volatile("s_barrier" ::: "memory");
        T = Tn;
    }
}

extern "C" void kernel_launch(void* const* d_in, const int* in_sizes, int n_in,
                              void* d_out, int out_size, void* d_ws, size_t ws_size,
                              hipStream_t stream) {
    const float* x    = (const float*)d_in[0];
    const float* W    = (const float*)d_in[1];
    const float* bias = (const float*)d_in[2];
    float* out = (float*)d_out;

    conv_pbc_kernel<<<dim3(NBLOCKS), dim3(256), 0, stream>>>(x, W, bias, out);
}